// Round 1
// baseline (260.617 us; speedup 1.0000x reference)
//
#include <hip/hip_runtime.h>
#include <hip/hip_bf16.h>
#include <stdint.h>

// Problem constants (B=2, T=2048, D=1024, H=16, DH=64)
#define Bn  2
#define Tn  2048
#define Dn  1024
#define Hn  16
#define DHn 64

typedef unsigned short u16;
typedef __attribute__((ext_vector_type(8))) short s16x8;            // 8 bf16 (4 VGPR) MFMA frag
typedef __attribute__((ext_vector_type(8))) unsigned short u16x8;
typedef __attribute__((ext_vector_type(4))) float f32x4;

#define MFMA(a, b, c) __builtin_amdgcn_mfma_f32_16x16x32_bf16((a), (b), (c), 0, 0, 0)

__device__ __forceinline__ u16 f2bf(float f) {
  union { __hip_bfloat16 b; u16 u; } c;
  c.b = __float2bfloat16(f);
  return c.u;
}

__device__ __forceinline__ u16x8 pack8(float4 a, float4 b) {
  u16x8 v;
  v[0] = f2bf(a.x); v[1] = f2bf(a.y); v[2] = f2bf(a.z); v[3] = f2bf(a.w);
  v[4] = f2bf(b.x); v[5] = f2bf(b.y); v[6] = f2bf(b.z); v[7] = f2bf(b.w);
  return v;
}

// ---------------------------------------------------------------------------
// Kernel 1: qkv = x @ W_qkv^T  (M=4096, N=3072, K=1024), RoPE epilogue.
// Writes Q,K as bf16 [b,h,t,dh]; V as bf16 transposed [b,h,dh,t].
// 128x128 tile, BK=64, 4 waves (2x2), per-wave 4x4 frags of 16x16x32.
// ---------------------------------------------------------------------------
__global__ __launch_bounds__(256) void k_qkv(
    const float* __restrict__ x, const float* __restrict__ wqkv,
    const int* __restrict__ tokpos,
    const float* __restrict__ cosc, const float* __restrict__ sinc,
    u16* __restrict__ qb, u16* __restrict__ kb, u16* __restrict__ vtb)
{
  __shared__ u16 As[128 * 72];   // +8 pad: row stride 144B = 36 banks -> conflict-free b128
  __shared__ u16 Bs[128 * 72];
  const int tid  = threadIdx.x;
  const int bcol = blockIdx.x;          // 24 tiles of N=3072
  const int brow = blockIdx.y;          // 32 tiles of M=4096
  const int lane = tid & 63, w = tid >> 6;
  const int wr = w >> 1, wc = w & 1;
  const int l15 = lane & 15, l4 = lane >> 4;
  const int srow = tid >> 3, scol = (tid & 7) * 8;

  f32x4 acc[4][4] = {};

  for (int k0 = 0; k0 < 1024; k0 += 64) {
#pragma unroll
    for (int p = 0; p < 4; ++p) {
      const int row = p * 32 + srow;
      const float* ga = x    + (size_t)(brow * 128 + row) * 1024 + k0 + scol;
      const float* gb = wqkv + (size_t)(bcol * 128 + row) * 1024 + k0 + scol;
      float4 a0 = *(const float4*)ga;
      float4 a1 = *(const float4*)(ga + 4);
      float4 b0 = *(const float4*)gb;
      float4 b1 = *(const float4*)(gb + 4);
      *(u16x8*)&As[row * 72 + scol] = pack8(a0, a1);
      *(u16x8*)&Bs[row * 72 + scol] = pack8(b0, b1);
    }
    __syncthreads();
#pragma unroll
    for (int kk = 0; kk < 64; kk += 32) {
      s16x8 af[4], bf[4];
#pragma unroll
      for (int m = 0; m < 4; ++m)
        af[m] = *(const s16x8*)&As[(wr * 64 + m * 16 + l15) * 72 + kk + l4 * 8];
#pragma unroll
      for (int n = 0; n < 4; ++n)
        bf[n] = *(const s16x8*)&Bs[(wc * 64 + n * 16 + l15) * 72 + kk + l4 * 8];
#pragma unroll
      for (int m = 0; m < 4; ++m)
#pragma unroll
        for (int n = 0; n < 4; ++n)
          acc[m][n] = MFMA(af[m], bf[n], acc[m][n]);
    }
    __syncthreads();
  }

  // Epilogue: C/D layout col=lane&15, row=(lane>>4)*4+r  (m89-verified)
#pragma unroll
  for (int m = 0; m < 4; ++m) {
    const int rowb = brow * 128 + wr * 64 + m * 16 + l4 * 4;
#pragma unroll
    for (int n = 0; n < 4; ++n) {
      const int colg  = bcol * 128 + wc * 64 + n * 16 + l15;
      const int which = colg >> 10;        // 0=Q 1=K 2=V (wave-uniform)
      const int rem   = colg & 1023;
      const int h = rem >> 6, dh = rem & 63;
#pragma unroll
      for (int r = 0; r < 4; ++r) {
        const int rowg = rowb + r;
        const int b = rowg >> 11, t = rowg & 2047;
        float v = acc[m][n][r];
        if (which < 2) {
          // RoPE: pair (dh even, dh odd) lives in lanes (l, l^1)
          const int pos = tokpos[t];
          const int fi  = dh >> 1;
          const float cv = cosc[pos * 32 + fi];
          const float sv = sinc[pos * 32 + fi];
          const float partner = __shfl_xor(v, 1);
          const float res = (dh & 1) ? fmaf(partner, sv, v * cv)    // x1*sin + x2*cos
                                     : fmaf(-partner, sv, v * cv);  // x1*cos - x2*sin
          u16* dst = (which == 0) ? qb : kb;
          dst[((size_t)(b * Hn + h) * Tn + t) * DHn + dh] = f2bf(res);
        } else {
          vtb[((size_t)(b * Hn + h) * DHn + dh) * Tn + t] = f2bf(v);
        }
      }
    }
  }
}

// ---------------------------------------------------------------------------
// Kernel 2: causal flash attention. Grid (T/64, B*H). 4 waves/block, each
// wave owns 16 q-rows. KV tiles of 32 staged in LDS (shared by all 4 waves).
// ---------------------------------------------------------------------------
__global__ __launch_bounds__(256) void k_attn(
    const u16* __restrict__ qb, const u16* __restrict__ kb,
    const u16* __restrict__ vtb, u16* __restrict__ ob)
{
  __shared__ u16 Ks[32][72];      // [kv][dh]  (+8 pad)
  __shared__ u16 Vs[64][40];      // [dh][kv]  (+8 pad)
  __shared__ u16 Ps[4][16][40];   // per-wave P relayout buffer

  const int tid  = threadIdx.x;
  const int lane = tid & 63, w = tid >> 6;
  const int l15 = lane & 15, l4 = lane >> 4;
  const int qblk = (int)(gridDim.x - 1) - (int)blockIdx.x;  // heavy blocks first
  const int bh   = blockIdx.y;
  const int b = bh >> 4, h = bh & 15;

  const u16* Qh = qb  + (size_t)bh * Tn * DHn;
  const u16* Kh = kb  + (size_t)bh * Tn * DHn;
  const u16* Vh = vtb + (size_t)bh * DHn * Tn;

  const int q0 = qblk * 64 + w * 16;

  // Q fragments hoisted (A-frag: row=l15, k=(l>>4)*8 contiguous)
  s16x8 qf0 = *(const s16x8*)(Qh + (size_t)(q0 + l15) * 64 + l4 * 8);
  s16x8 qf1 = *(const s16x8*)(Qh + (size_t)(q0 + l15) * 64 + 32 + l4 * 8);

  f32x4 o[4] = {};
  float mr[4], lr[4];
#pragma unroll
  for (int r = 0; r < 4; ++r) { mr[r] = -3.0e38f; lr[r] = 0.0f; }

  const int ntiles = qblk * 2 + 2;                // covers causal window of all 4 waves
  const int krow = tid >> 3, kcol = (tid & 7) * 8;
  const int vrow = tid >> 2, vcol = (tid & 3) * 8;

  for (int it = 0; it < ntiles; ++it) {
    const int kv0 = it * 32;
    __syncthreads();
    *(uint4*)&Ks[krow][kcol] = *(const uint4*)(Kh + (size_t)(kv0 + krow) * 64 + kcol);
    *(uint4*)&Vs[vrow][vcol] = *(const uint4*)(Vh + (size_t)vrow * Tn + kv0 + vcol);
    __syncthreads();

    // S = Q K^T  (2 col-halves x 2 k-steps)
    f32x4 s[2] = {};
#pragma unroll
    for (int half = 0; half < 2; ++half) {
      s16x8 kf0 = *(const s16x8*)&Ks[half * 16 + l15][l4 * 8];
      s16x8 kf1 = *(const s16x8*)&Ks[half * 16 + l15][32 + l4 * 8];
      s[half] = MFMA(qf0, kf0, s[half]);
      s[half] = MFMA(qf1, kf1, s[half]);
    }

    // scale + causal mask + tile row-max
    float tmax[4] = {-3.0e38f, -3.0e38f, -3.0e38f, -3.0e38f};
#pragma unroll
    for (int half = 0; half < 2; ++half)
#pragma unroll
      for (int r = 0; r < 4; ++r) {
        const int kvtok = kv0 + half * 16 + l15;
        const int qtok  = q0 + l4 * 4 + r;
        float sv = s[half][r] * 0.125f;
        sv = (kvtok <= qtok) ? sv : -3.0e38f;
        s[half][r] = sv;
        tmax[r] = fmaxf(tmax[r], sv);
      }
#pragma unroll
    for (int r = 0; r < 4; ++r) {
      tmax[r] = fmaxf(tmax[r], __shfl_xor(tmax[r], 1));
      tmax[r] = fmaxf(tmax[r], __shfl_xor(tmax[r], 2));
      tmax[r] = fmaxf(tmax[r], __shfl_xor(tmax[r], 4));
      tmax[r] = fmaxf(tmax[r], __shfl_xor(tmax[r], 8));
      const float mnew  = fmaxf(mr[r], tmax[r]);
      const float alpha = __expf(mr[r] - mnew);
      mr[r] = mnew;
      lr[r] *= alpha;
      o[0][r] *= alpha; o[1][r] *= alpha; o[2][r] *= alpha; o[3][r] *= alpha;
    }

    // P = exp(S - m); lane-partial l; relayout C->A frag through LDS
#pragma unroll
    for (int half = 0; half < 2; ++half)
#pragma unroll
      for (int r = 0; r < 4; ++r) {
        const float p = __expf(s[half][r] - mr[r]);
        lr[r] += p;
        Ps[w][l4 * 4 + r][half * 16 + l15] = f2bf(p);
      }
    s16x8 pf = *(const s16x8*)&Ps[w][l15][l4 * 8];

    // O += P V   (V^T rows are contiguous kv)
#pragma unroll
    for (int n = 0; n < 4; ++n) {
      s16x8 vf = *(const s16x8*)&Vs[n * 16 + l15][l4 * 8];
      o[n] = MFMA(pf, vf, o[n]);
    }
  }

  // final l reduction across the 16-lane row group; normalize; store O bf16 [b,t,h,dh]
#pragma unroll
  for (int r = 0; r < 4; ++r) {
    lr[r] += __shfl_xor(lr[r], 1);
    lr[r] += __shfl_xor(lr[r], 2);
    lr[r] += __shfl_xor(lr[r], 4);
    lr[r] += __shfl_xor(lr[r], 8);
  }
#pragma unroll
  for (int r = 0; r < 4; ++r) {
    const int t = q0 + l4 * 4 + r;
    const float inv = 1.0f / lr[r];
#pragma unroll
    for (int n = 0; n < 4; ++n)
      ob[(size_t)(b * Tn + t) * Dn + h * 64 + n * 16 + l15] = f2bf(o[n][r] * inv);
  }
}

// ---------------------------------------------------------------------------
// Kernel 3: out = O @ W_o^T  (M=4096, N=1024, K=1024), fp32 output.
// ---------------------------------------------------------------------------
__global__ __launch_bounds__(256) void k_out(
    const u16* __restrict__ ob, const float* __restrict__ wo,
    float* __restrict__ out)
{
  __shared__ u16 As[128 * 72];
  __shared__ u16 Bs[128 * 72];
  const int tid  = threadIdx.x;
  const int bcol = blockIdx.x;          // 8
  const int brow = blockIdx.y;          // 32
  const int lane = tid & 63, w = tid >> 6;
  const int wr = w >> 1, wc = w & 1;
  const int l15 = lane & 15, l4 = lane >> 4;
  const int srow = tid >> 3, scol = (tid & 7) * 8;

  f32x4 acc[4][4] = {};

  for (int k0 = 0; k0 < 1024; k0 += 64) {
#pragma unroll
    for (int p = 0; p < 4; ++p) {
      const int row = p * 32 + srow;
      *(u16x8*)&As[row * 72 + scol] =
          *(const u16x8*)(ob + (size_t)(brow * 128 + row) * 1024 + k0 + scol);
      const float* gb = wo + (size_t)(bcol * 128 + row) * 1024 + k0 + scol;
      float4 b0 = *(const float4*)gb;
      float4 b1 = *(const float4*)(gb + 4);
      *(u16x8*)&Bs[row * 72 + scol] = pack8(b0, b1);
    }
    __syncthreads();
#pragma unroll
    for (int kk = 0; kk < 64; kk += 32) {
      s16x8 af[4], bf[4];
#pragma unroll
      for (int m = 0; m < 4; ++m)
        af[m] = *(const s16x8*)&As[(wr * 64 + m * 16 + l15) * 72 + kk + l4 * 8];
#pragma unroll
      for (int n = 0; n < 4; ++n)
        bf[n] = *(const s16x8*)&Bs[(wc * 64 + n * 16 + l15) * 72 + kk + l4 * 8];
#pragma unroll
      for (int m = 0; m < 4; ++m)
#pragma unroll
        for (int n = 0; n < 4; ++n)
          acc[m][n] = MFMA(af[m], bf[n], acc[m][n]);
    }
    __syncthreads();
  }

#pragma unroll
  for (int m = 0; m < 4; ++m) {
    const int rowb = brow * 128 + wr * 64 + m * 16 + l4 * 4;
#pragma unroll
    for (int n = 0; n < 4; ++n) {
      const int colg = bcol * 128 + wc * 64 + n * 16 + l15;
#pragma unroll
      for (int r = 0; r < 4; ++r)
        out[(size_t)(rowb + r) * 1024 + colg] = acc[m][n][r];
    }
  }
}

// ---------------------------------------------------------------------------
extern "C" void kernel_launch(void* const* d_in, const int* in_sizes, int n_in,
                              void* d_out, int out_size, void* d_ws, size_t ws_size,
                              hipStream_t stream) {
  const float* x      = (const float*)d_in[0];
  const int*   tokpos = (const int*)d_in[1];
  const float* wqkv   = (const float*)d_in[2];
  const float* wo     = (const float*)d_in[3];
  const float* cosc   = (const float*)d_in[4];
  const float* sinc   = (const float*)d_in[5];
  float* out = (float*)d_out;

  // workspace: Q, K, Vt, O  (bf16, each B*T*D = 4194304 elems = 8 MB) -> 33.6 MB
  u16* qb  = (u16*)d_ws;
  u16* kb  = qb  + (size_t)Bn * Tn * Dn;
  u16* vtb = kb  + (size_t)Bn * Tn * Dn;
  u16* ob  = vtb + (size_t)Bn * Tn * Dn;

  dim3 blk(256);
  dim3 g1(24, 32);   // N/128, M/128
  k_qkv<<<g1, blk, 0, stream>>>(x, wqkv, tokpos, cosc, sinc, qb, kb, vtb);

  dim3 g2(Tn / 64, Bn * Hn);
  k_attn<<<g2, blk, 0, stream>>>(qb, kb, vtb, ob);

  dim3 g3(8, 32);    // N/128, M/128
  k_out<<<g3, blk, 0, stream>>>(ob, wo, out);
}

// Round 2
// 180.917 us; speedup vs baseline: 1.4405x; 1.4405x over previous
//
#include <hip/hip_runtime.h>
#include <hip/hip_bf16.h>
#include <stdint.h>

// Problem constants (B=2, T=2048, D=1024, H=16, DH=64)
#define Bn  2
#define Tn  2048
#define Dn  1024
#define Hn  16
#define DHn 64
#define QSCALE 0.1803368801111204f   // 0.125 * log2(e): fold softmax scale + exp2 conversion into Q

typedef unsigned short u16;
typedef __attribute__((ext_vector_type(8))) short s16x8;            // 8 bf16 MFMA frag (4 VGPR)
typedef __attribute__((ext_vector_type(8))) unsigned short u16x8;
typedef __attribute__((ext_vector_type(4))) unsigned short u16x4;
typedef __attribute__((ext_vector_type(4))) float f32x4;

#define MFMA(a, b, c) __builtin_amdgcn_mfma_f32_16x16x32_bf16((a), (b), (c), 0, 0, 0)

__device__ __forceinline__ u16 f2bf(float f) {
  union { __hip_bfloat16 b; u16 u; } c;
  c.b = __float2bfloat16(f);
  return c.u;
}

__device__ __forceinline__ u16x8 pack8(float4 a, float4 b) {
  u16x8 v;
  v[0] = f2bf(a.x); v[1] = f2bf(a.y); v[2] = f2bf(a.z); v[3] = f2bf(a.w);
  v[4] = f2bf(b.x); v[5] = f2bf(b.y); v[6] = f2bf(b.z); v[7] = f2bf(b.w);
  return v;
}

// async global->LDS, 16B per lane; LDS dest must be wave-uniform base (HW adds lane*16)
__device__ __forceinline__ void lds16(void* lds, const void* g) {
  __builtin_amdgcn_global_load_lds((__attribute__((address_space(1))) void*)(g),
                                   (__attribute__((address_space(3))) void*)(lds), 16, 0, 0);
}

// ---------------------------------------------------------------------------
// fp32 -> bf16 bulk convert (vectorized, grid-stride)
// ---------------------------------------------------------------------------
__global__ __launch_bounds__(256) void k_cvt(const float* __restrict__ src,
                                             u16* __restrict__ dst, int n4) {
  int i = blockIdx.x * blockDim.x + threadIdx.x;
  const int stride = gridDim.x * blockDim.x;
  for (; i < n4; i += stride) {
    float4 v = ((const float4*)src)[i];
    u16x4 o;
    o[0] = f2bf(v.x); o[1] = f2bf(v.y); o[2] = f2bf(v.z); o[3] = f2bf(v.w);
    ((u16x4*)dst)[i] = o;
  }
}

// ---------------------------------------------------------------------------
// Kernel 1: qkv = x @ W_qkv^T (M=4096, N=3072, K=1024), bf16 in via
// global_load_lds (m97 structure), RoPE epilogue. Q pre-scaled by QSCALE.
// Writes Q,K bf16 [b,h,t,dh]; V bf16 transposed [b,h,dh,t].
// ---------------------------------------------------------------------------
__global__ __launch_bounds__(256) void k_qkv(
    const u16* __restrict__ xb, const u16* __restrict__ wb,
    const int* __restrict__ tokpos,
    const float* __restrict__ cosc, const float* __restrict__ sinc,
    u16* __restrict__ qb, u16* __restrict__ kb, u16* __restrict__ vtb)
{
  __shared__ u16 As[128 * 64];   // linear: global_load_lds writes base+lane*16
  __shared__ u16 Bs[128 * 64];
  const int tid  = threadIdx.x;
  const int bcol = blockIdx.x;          // 24 tiles of N=3072
  const int brow = blockIdx.y;          // 32 tiles of M=4096
  const int lane = tid & 63, w = tid >> 6;
  const int wr = w >> 1, wc = w & 1;
  const int l15 = lane & 15, l4 = lane >> 4;
  const int lrow = lane >> 3, lcol = (lane & 7) * 8;

  f32x4 acc[4][4] = {};

  for (int k0 = 0; k0 < 1024; k0 += 64) {
#pragma unroll
    for (int c = 0; c < 4; ++c) {
      const int row = w * 32 + c * 8;   // wave-uniform
      lds16(&As[row * 64], xb + (size_t)(brow * 128 + row + lrow) * 1024 + k0 + lcol);
      lds16(&Bs[row * 64], wb + (size_t)(bcol * 128 + row + lrow) * 1024 + k0 + lcol);
    }
    __syncthreads();
#pragma unroll
    for (int kk = 0; kk < 64; kk += 32) {
      s16x8 af[4], bf[4];
#pragma unroll
      for (int m = 0; m < 4; ++m)
        af[m] = *(const s16x8*)&As[(wr * 64 + m * 16 + l15) * 64 + kk + l4 * 8];
#pragma unroll
      for (int n = 0; n < 4; ++n)
        bf[n] = *(const s16x8*)&Bs[(wc * 64 + n * 16 + l15) * 64 + kk + l4 * 8];
#pragma unroll
      for (int m = 0; m < 4; ++m)
#pragma unroll
        for (int n = 0; n < 4; ++n)
          acc[m][n] = MFMA(af[m], bf[n], acc[m][n]);
    }
    __syncthreads();
  }

  // Epilogue: C/D layout col=lane&15, row=(lane>>4)*4+r
#pragma unroll
  for (int m = 0; m < 4; ++m) {
    const int rowb = brow * 128 + wr * 64 + m * 16 + l4 * 4;
#pragma unroll
    for (int n = 0; n < 4; ++n) {
      const int colg  = bcol * 128 + wc * 64 + n * 16 + l15;
      const int which = colg >> 10;        // 0=Q 1=K 2=V (wave-uniform)
      const int rem   = colg & 1023;
      const int h = rem >> 6, dh = rem & 63;
#pragma unroll
      for (int r = 0; r < 4; ++r) {
        const int rowg = rowb + r;
        const int b = rowg >> 11, t = rowg & 2047;
        float v = acc[m][n][r];
        if (which < 2) {
          const int pos = tokpos[t];
          const int fi  = dh >> 1;
          const float cv = cosc[pos * 32 + fi];
          const float sv = sinc[pos * 32 + fi];
          const float partner = __shfl_xor(v, 1);
          float res = (dh & 1) ? fmaf(partner, sv, v * cv)
                               : fmaf(-partner, sv, v * cv);
          u16* dst;
          if (which == 0) { dst = qb; res *= QSCALE; } else dst = kb;
          dst[((size_t)(b * Hn + h) * Tn + t) * DHn + dh] = f2bf(res);
        } else {
          vtb[((size_t)(b * Hn + h) * DHn + dh) * Tn + t] = f2bf(v);
        }
      }
    }
  }
}

// ---------------------------------------------------------------------------
// Kernel 2: causal flash attention, swapped-QK^T, KVBLK=64, double-buffered
// LDS with reg prefetch (1 barrier/tile), paired q-tiles for balance.
// Grid (16, B*H). 4 waves/block, each wave owns 16 q-rows.
// ---------------------------------------------------------------------------
__global__ __launch_bounds__(256) void k_attn(
    const u16* __restrict__ qbuf, const u16* __restrict__ kbuf,
    const u16* __restrict__ vtb, u16* __restrict__ ob)
{
  __shared__ u16 Ks[2][64][72];   // [buf][kv][dh]   (+8 pad)
  __shared__ u16 Vs[2][64][72];   // [buf][dh][kv]   (+8 pad)
  __shared__ u16 Ps[4][16][72];   // per-wave P^T relayout [q][kv]

  const int tid  = threadIdx.x;
  const int lane = tid & 63, w = tid >> 6;
  const int l15 = lane & 15, l4 = lane >> 4;
  const int bx = blockIdx.x;           // 0..15
  const int bh = blockIdx.y;
  const int b = bh >> 4, h = bh & 15;

  const u16* Qh = qbuf + (size_t)bh * Tn * DHn;
  const u16* Kh = kbuf + (size_t)bh * Tn * DHn;
  const u16* Vh = vtb  + (size_t)bh * DHn * Tn;

  const int srow = tid >> 3, scol = (tid & 7) * 8;   // staging coords (32 rows x 8 lanes)

  for (int seg = 0; seg < 2; ++seg) {
    const int qblk = seg ? (31 - bx) : bx;           // paired: total tiles uniform (33)
    const int q0 = qblk * 64 + w * 16;
    const int ntiles = qblk + 1;

    const s16x8 qf0 = *(const s16x8*)(Qh + (size_t)(q0 + l15) * 64 + l4 * 8);
    const s16x8 qf1 = *(const s16x8*)(Qh + (size_t)(q0 + l15) * 64 + 32 + l4 * 8);

    f32x4 o[4] = {};
    float m = -3.0e38f, lr = 0.0f;

    // prefetch tile 0 into regs, then LDS buf0 (barrier protects prev-seg readers)
    uint4 ka0 = *(const uint4*)(Kh + (size_t)(srow)      * 64 + scol);
    uint4 ka1 = *(const uint4*)(Kh + (size_t)(srow + 32) * 64 + scol);
    uint4 va0 = *(const uint4*)(Vh + (size_t)(srow)      * Tn + scol);
    uint4 va1 = *(const uint4*)(Vh + (size_t)(srow + 32) * Tn + scol);
    __syncthreads();
    *(uint4*)&Ks[0][srow][scol]      = ka0;
    *(uint4*)&Ks[0][srow + 32][scol] = ka1;
    *(uint4*)&Vs[0][srow][scol]      = va0;
    *(uint4*)&Vs[0][srow + 32][scol] = va1;

    for (int it = 0; it < ntiles; ++it) {
      const int buf = it & 1;
      __syncthreads();                 // buf ready for all waves
      if (it + 1 < ntiles) {           // issue next tile's loads (latency hidden)
        const int kv1 = (it + 1) * 64;
        ka0 = *(const uint4*)(Kh + (size_t)(kv1 + srow)      * 64 + scol);
        ka1 = *(const uint4*)(Kh + (size_t)(kv1 + srow + 32) * 64 + scol);
        va0 = *(const uint4*)(Vh + (size_t)(srow)      * Tn + kv1 + scol);
        va1 = *(const uint4*)(Vh + (size_t)(srow + 32) * Tn + kv1 + scol);
      }

      // S^T = K Q^T : lane holds q=l15 col; kv = hh*16 + l4*4 + r
      f32x4 s[4] = {};
      __builtin_amdgcn_s_setprio(1);
#pragma unroll
      for (int ks = 0; ks < 2; ++ks) {
        const s16x8 qf = ks ? qf1 : qf0;
#pragma unroll
        for (int hh = 0; hh < 4; ++hh) {
          const s16x8 kf = *(const s16x8*)&Ks[buf][hh * 16 + l15][ks * 32 + l4 * 8];
          s[hh] = MFMA(kf, qf, s[hh]);
        }
      }
      __builtin_amdgcn_s_setprio(0);

      if (it == ntiles - 1) {          // diagonal tile: causal mask
        const int kvb = it * 64 + l4 * 4;
        const int qg  = q0 + l15;
#pragma unroll
        for (int hh = 0; hh < 4; ++hh)
#pragma unroll
          for (int r = 0; r < 4; ++r)
            if (kvb + hh * 16 + r > qg) s[hh][r] = -3.0e38f;
      }

      // in-lane row max (16 vals) + 2 shfl across l4 groups
      float tmax = -3.0e38f;
#pragma unroll
      for (int hh = 0; hh < 4; ++hh)
#pragma unroll
        for (int r = 0; r < 4; ++r) tmax = fmaxf(tmax, s[hh][r]);
      tmax = fmaxf(tmax, __shfl_xor(tmax, 16));
      tmax = fmaxf(tmax, __shfl_xor(tmax, 32));

      // defer-max: only rescale when max grew by >8 (exp2 domain)
      if (__any(tmax > m + 8.0f)) {
        const float mn    = fmaxf(m, tmax);
        const float alpha = __builtin_amdgcn_exp2f(m - mn);
        m = mn;
        lr *= alpha;
#pragma unroll
        for (int n = 0; n < 4; ++n)
#pragma unroll
          for (int r = 0; r < 4; ++r) o[n][r] *= alpha;
      }

      // P = exp2(S - m), lane-partial sum, pack 4 bf16 -> one b64 LDS write per hh
#pragma unroll
      for (int hh = 0; hh < 4; ++hh) {
        u16x4 pk;
#pragma unroll
        for (int r = 0; r < 4; ++r) {
          const float p = __builtin_amdgcn_exp2f(s[hh][r] - m);
          lr += p;
          pk[r] = f2bf(p);
        }
        *(u16x4*)&Ps[w][l15][hh * 16 + l4 * 4] = pk;
      }

      // O^T += V^T P^T   (af = V^T rows dh, bf = P^T rows q)
      const s16x8 pf0 = *(const s16x8*)&Ps[w][l15][l4 * 8];
      const s16x8 pf1 = *(const s16x8*)&Ps[w][l15][32 + l4 * 8];
      __builtin_amdgcn_s_setprio(1);
#pragma unroll
      for (int n = 0; n < 4; ++n) {
        const s16x8 vf0 = *(const s16x8*)&Vs[buf][n * 16 + l15][l4 * 8];
        const s16x8 vf1 = *(const s16x8*)&Vs[buf][n * 16 + l15][32 + l4 * 8];
        o[n] = MFMA(vf0, pf0, o[n]);
        o[n] = MFMA(vf1, pf1, o[n]);
      }
      __builtin_amdgcn_s_setprio(0);

      if (it + 1 < ntiles) {           // write prefetched regs to other buffer
        const int nb = buf ^ 1;
        *(uint4*)&Ks[nb][srow][scol]      = ka0;
        *(uint4*)&Ks[nb][srow + 32][scol] = ka1;
        *(uint4*)&Vs[nb][srow][scol]      = va0;
        *(uint4*)&Vs[nb][srow + 32][scol] = va1;
      }
    }

    // combine lane-partial l across l4 groups; normalize; store O bf16 [b,t,h*64+dh]
    lr += __shfl_xor(lr, 16);
    lr += __shfl_xor(lr, 32);
    const float inv = 1.0f / lr;
    const int t = q0 + l15;
#pragma unroll
    for (int n = 0; n < 4; ++n) {
      u16x4 ov;
#pragma unroll
      for (int r = 0; r < 4; ++r) ov[r] = f2bf(o[n][r] * inv);
      *(u16x4*)(ob + (size_t)(b * Tn + t) * Dn + h * 64 + n * 16 + l4 * 4) = ov;
    }
  }
}

// ---------------------------------------------------------------------------
// Kernel 3: out = O @ W_o^T (M=4096, N=1024, K=1024). A (bf16) via
// global_load_lds; B (fp32 W_o) reg-staged + converted; fp32 output.
// ---------------------------------------------------------------------------
__global__ __launch_bounds__(256) void k_out(
    const u16* __restrict__ ob, const float* __restrict__ wo,
    float* __restrict__ out)
{
  __shared__ u16 As[128 * 64];   // linear (global_load_lds)
  __shared__ u16 Bs[128 * 72];   // padded (reg-staged)
  const int tid  = threadIdx.x;
  const int bcol = blockIdx.x;          // 8
  const int brow = blockIdx.y;          // 32
  const int lane = tid & 63, w = tid >> 6;
  const int wr = w >> 1, wc = w & 1;
  const int l15 = lane & 15, l4 = lane >> 4;
  const int lrow = lane >> 3, lcol = (lane & 7) * 8;
  const int srow = tid >> 3, scol = (tid & 7) * 8;

  f32x4 acc[4][4] = {};

  for (int k0 = 0; k0 < 1024; k0 += 64) {
#pragma unroll
    for (int c = 0; c < 4; ++c) {
      const int row = w * 32 + c * 8;
      lds16(&As[row * 64], ob + (size_t)(brow * 128 + row + lrow) * 1024 + k0 + lcol);
    }
#pragma unroll
    for (int p = 0; p < 4; ++p) {
      const int row = p * 32 + srow;
      const float* gb = wo + (size_t)(bcol * 128 + row) * 1024 + k0 + scol;
      float4 b0 = *(const float4*)gb;
      float4 b1 = *(const float4*)(gb + 4);
      *(u16x8*)&Bs[row * 72 + scol] = pack8(b0, b1);
    }
    __syncthreads();
#pragma unroll
    for (int kk = 0; kk < 64; kk += 32) {
      s16x8 af[4], bf[4];
#pragma unroll
      for (int m = 0; m < 4; ++m)
        af[m] = *(const s16x8*)&As[(wr * 64 + m * 16 + l15) * 64 + kk + l4 * 8];
#pragma unroll
      for (int n = 0; n < 4; ++n)
        bf[n] = *(const s16x8*)&Bs[(wc * 64 + n * 16 + l15) * 72 + kk + l4 * 8];
#pragma unroll
      for (int m = 0; m < 4; ++m)
#pragma unroll
        for (int n = 0; n < 4; ++n)
          acc[m][n] = MFMA(af[m], bf[n], acc[m][n]);
    }
    __syncthreads();
  }

#pragma unroll
  for (int m = 0; m < 4; ++m) {
    const int rowb = brow * 128 + wr * 64 + m * 16 + l4 * 4;
#pragma unroll
    for (int n = 0; n < 4; ++n) {
      const int colg = bcol * 128 + wc * 64 + n * 16 + l15;
#pragma unroll
      for (int r = 0; r < 4; ++r)
        out[(size_t)(rowb + r) * 1024 + colg] = acc[m][n][r];
    }
  }
}

// ---------------------------------------------------------------------------
extern "C" void kernel_launch(void* const* d_in, const int* in_sizes, int n_in,
                              void* d_out, int out_size, void* d_ws, size_t ws_size,
                              hipStream_t stream) {
  const float* x      = (const float*)d_in[0];
  const int*   tokpos = (const int*)d_in[1];
  const float* wqkv   = (const float*)d_in[2];
  const float* wo     = (const float*)d_in[3];
  const float* cosc   = (const float*)d_in[4];
  const float* sinc   = (const float*)d_in[5];
  float* out = (float*)d_out;

  // workspace (u16 units): xb 4M (aliased by ob later), wqkvb 3M, qb/kb/vtb 4M each = 38 MB
  u16* xb     = (u16*)d_ws;
  u16* wqkvb  = xb + (size_t)Bn * Tn * Dn;
  u16* qb     = wqkvb + (size_t)3 * Dn * Dn;
  u16* kb     = qb + (size_t)Bn * Tn * Dn;
  u16* vtb    = kb + (size_t)Bn * Tn * Dn;
  u16* ob     = xb;   // xb dead after k_qkv

  dim3 blk(256);
  k_cvt<<<dim3(2048), blk, 0, stream>>>(x,    xb,    (Bn * Tn * Dn) / 4);
  k_cvt<<<dim3(2048), blk, 0, stream>>>(wqkv, wqkvb, (3 * Dn * Dn) / 4);

  k_qkv<<<dim3(24, 32), blk, 0, stream>>>(xb, wqkvb, tokpos, cosc, sinc, qb, kb, vtb);

  k_attn<<<dim3(16, Bn * Hn), blk, 0, stream>>>(qb, kb, vtb, ob);

  k_out<<<dim3(8, 32), blk, 0, stream>>>(ob, wo, out);
}

// Round 3
// 163.823 us; speedup vs baseline: 1.5908x; 1.1043x over previous
//
#include <hip/hip_runtime.h>
#include <hip/hip_bf16.h>
#include <stdint.h>

// Problem constants (B=2, T=2048, D=1024, H=16, DH=64)
#define Bn  2
#define Tn  2048
#define Dn  1024
#define Hn  16
#define DHn 64
#define QSCALE 0.1803368801111204f   // 0.125 * log2(e): fold softmax scale + exp2 into Q

typedef unsigned short u16;
typedef __attribute__((ext_vector_type(8))) short s16x8;            // 8 bf16 MFMA frag
typedef __attribute__((ext_vector_type(8))) unsigned short u16x8;
typedef __attribute__((ext_vector_type(4))) unsigned short u16x4;
typedef __attribute__((ext_vector_type(4))) float f32x4;

#define MFMA(a, b, c) __builtin_amdgcn_mfma_f32_16x16x32_bf16((a), (b), (c), 0, 0, 0)

__device__ __forceinline__ u16 f2bf(float f) {
  union { __hip_bfloat16 b; u16 u; } c;
  c.b = __float2bfloat16(f);
  return c.u;
}
__device__ __forceinline__ float bf2f(u16 u) {
  union { u16 u; __hip_bfloat16 b; } c;
  c.u = u;
  return __bfloat162float(c.b);
}

// async global->LDS, 16B per lane; LDS dest is wave-uniform base (+lane*16)
__device__ __forceinline__ void lds16(void* lds, const void* g) {
  __builtin_amdgcn_global_load_lds((__attribute__((address_space(1))) void*)(g),
                                   (__attribute__((address_space(3))) void*)(lds), 16, 0, 0);
}

// ---------------------------------------------------------------------------
// fp32 -> bf16 bulk convert
// ---------------------------------------------------------------------------
__global__ __launch_bounds__(256) void k_cvt(const float* __restrict__ src,
                                             u16* __restrict__ dst, int n4) {
  int i = blockIdx.x * blockDim.x + threadIdx.x;
  const int stride = gridDim.x * blockDim.x;
  for (; i < n4; i += stride) {
    float4 v = ((const float4*)src)[i];
    u16x4 o;
    o[0] = f2bf(v.x); o[1] = f2bf(v.y); o[2] = f2bf(v.z); o[3] = f2bf(v.w);
    ((u16x4*)dst)[i] = o;
  }
}

// ---------------------------------------------------------------------------
// Kernel 1: qkv = x @ W_qkv^T (M=4096, N=3072, K=1024), m97 main loop.
// Epilogue: LDS repack -> in-register RoPE -> coalesced 16B stores.
// Q,K,V all written bf16 row-major [b,h,t,dh]; Q pre-scaled by QSCALE.
// ---------------------------------------------------------------------------
__global__ __launch_bounds__(256) void k_qkv(
    const u16* __restrict__ xb, const u16* __restrict__ wb,
    const int* __restrict__ tokpos,
    const float* __restrict__ cosc, const float* __restrict__ sinc,
    u16* __restrict__ qb, u16* __restrict__ kb, u16* __restrict__ vb)
{
  __shared__ u16 smem[128 * 128];       // 32KB: main loop As|Bs, epilogue Ct[128][128]
  u16* As = smem;                       // [128][64] linear (global_load_lds)
  u16* Bs = smem + 128 * 64;
  const int tid  = threadIdx.x;
  const int bcol = blockIdx.x;          // 24 tiles of N=3072
  const int brow = blockIdx.y;          // 32 tiles of M=4096
  const int lane = tid & 63, w = tid >> 6;
  const int wr = w >> 1, wc = w & 1;
  const int l15 = lane & 15, l4 = lane >> 4;
  const int lrow = lane >> 3, lcol = (lane & 7) * 8;

  f32x4 acc[4][4] = {};

  for (int k0 = 0; k0 < 1024; k0 += 64) {
#pragma unroll
    for (int c = 0; c < 4; ++c) {
      const int row = w * 32 + c * 8;   // wave-uniform
      lds16(&As[row * 64], xb + (size_t)(brow * 128 + row + lrow) * 1024 + k0 + lcol);
      lds16(&Bs[row * 64], wb + (size_t)(bcol * 128 + row + lrow) * 1024 + k0 + lcol);
    }
    __syncthreads();
#pragma unroll
    for (int kk = 0; kk < 64; kk += 32) {
      s16x8 af[4], bf[4];
#pragma unroll
      for (int m = 0; m < 4; ++m)
        af[m] = *(const s16x8*)&As[(wr * 64 + m * 16 + l15) * 64 + kk + l4 * 8];
#pragma unroll
      for (int n = 0; n < 4; ++n)
        bf[n] = *(const s16x8*)&Bs[(wc * 64 + n * 16 + l15) * 64 + kk + l4 * 8];
#pragma unroll
      for (int m = 0; m < 4; ++m)
#pragma unroll
        for (int n = 0; n < 4; ++n)
          acc[m][n] = MFMA(af[m], bf[n], acc[m][n]);
    }
    __syncthreads();
  }

  // ---- epilogue phase 1: raw acc -> Ct (bf16, stride 128) ----
#pragma unroll
  for (int m = 0; m < 4; ++m)
#pragma unroll
    for (int n = 0; n < 4; ++n)
#pragma unroll
      for (int r = 0; r < 4; ++r)
        smem[(wr * 64 + m * 16 + l4 * 4 + r) * 128 + wc * 64 + n * 16 + l15] =
            f2bf(acc[m][n][r]);
  __syncthreads();

  // ---- epilogue phase 2: re-read rows, RoPE in-register, coalesced store ----
#pragma unroll
  for (int ph = 0; ph < 8; ++ph) {
    const int task = ph * 256 + tid;
    const int lr   = task >> 4;          // 0..127
    const int cg   = task & 15;          // col group (8 elems)
    const int rowg = brow * 128 + lr;
    const int b = rowg >> 11, t = rowg & 2047;
    const int colg = bcol * 128 + cg * 8;
    const int which = colg >> 10;        // 0=Q 1=K 2=V (wave-uniform)
    const int rem = colg & 1023;
    const int h = rem >> 6, dh0 = rem & 63;
    u16x8 v = *(const u16x8*)&smem[lr * 128 + cg * 8];
    u16* dst = (which == 0) ? qb : (which == 1) ? kb : vb;
    u16* gp = dst + ((size_t)(b * Hn + h) * Tn + t) * DHn + dh0;
    if (which < 2) {
      const int pos = tokpos[t];
      const float4 cv = *(const float4*)&cosc[pos * 32 + (dh0 >> 1)];
      const float4 sv = *(const float4*)&sinc[pos * 32 + (dh0 >> 1)];
      const float cc[4] = {cv.x, cv.y, cv.z, cv.w};
      const float ss[4] = {sv.x, sv.y, sv.z, sv.w};
      const float sc = (which == 0) ? QSCALE : 1.0f;
      u16x8 o;
#pragma unroll
      for (int p = 0; p < 4; ++p) {
        const float x1 = bf2f(v[2 * p]), x2 = bf2f(v[2 * p + 1]);
        o[2 * p]     = f2bf((x1 * cc[p] - x2 * ss[p]) * sc);
        o[2 * p + 1] = f2bf((x1 * ss[p] + x2 * cc[p]) * sc);
      }
      *(u16x8*)gp = o;
    } else {
      *(u16x8*)gp = v;
    }
  }
}

// ---------------------------------------------------------------------------
// Kernel 2: causal flash attention, swapped-QK^T, KVBLK=64, double-buffered
// LDS with reg prefetch, paired q-tiles. V loaded row-major, transposed
// into LDS during staging. Grid (16, B*H).
// ---------------------------------------------------------------------------
__global__ __launch_bounds__(256) void k_attn(
    const u16* __restrict__ qbuf, const u16* __restrict__ kbuf,
    const u16* __restrict__ vbuf, u16* __restrict__ ob)
{
  __shared__ u16 Ks[2][64][72];   // [buf][kv][dh]
  __shared__ u16 Vs[2][64][72];   // [buf][dh][kv]
  __shared__ u16 Ps[4][16][72];   // per-wave P^T relayout [q][kv]

  const int tid  = threadIdx.x;
  const int lane = tid & 63, w = tid >> 6;
  const int l15 = lane & 15, l4 = lane >> 4;
  const int bx = blockIdx.x;
  const int bh = blockIdx.y;
  const int b = bh >> 4, h = bh & 15;

  const u16* Qh = qbuf + (size_t)bh * Tn * DHn;
  const u16* Kh = kbuf + (size_t)bh * Tn * DHn;
  const u16* Vh = vbuf + (size_t)bh * Tn * DHn;

  const int srow = tid >> 3, scol = (tid & 7) * 8;

  for (int seg = 0; seg < 2; ++seg) {
    const int qblk = seg ? (31 - bx) : bx;           // uniform 33 tiles/block
    const int q0 = qblk * 64 + w * 16;
    const int ntiles = qblk + 1;

    const s16x8 qf0 = *(const s16x8*)(Qh + (size_t)(q0 + l15) * 64 + l4 * 8);
    const s16x8 qf1 = *(const s16x8*)(Qh + (size_t)(q0 + l15) * 64 + 32 + l4 * 8);

    f32x4 o[4] = {};
    float m = -3.0e38f, lr = 0.0f;

    uint4 ka0 = *(const uint4*)(Kh + (size_t)(srow)      * 64 + scol);
    uint4 ka1 = *(const uint4*)(Kh + (size_t)(srow + 32) * 64 + scol);
    uint4 va0 = *(const uint4*)(Vh + (size_t)(srow)      * 64 + scol);
    uint4 va1 = *(const uint4*)(Vh + (size_t)(srow + 32) * 64 + scol);
    __syncthreads();
    *(uint4*)&Ks[0][srow][scol]      = ka0;
    *(uint4*)&Ks[0][srow + 32][scol] = ka1;
    {
      union { uint4 q; u16 e[8]; } u0, u1;
      u0.q = va0; u1.q = va1;
#pragma unroll
      for (int j = 0; j < 8; ++j) {
        Vs[0][scol + j][srow]      = u0.e[j];   // V[kv][dh] -> Vs[dh][kv]
        Vs[0][scol + j][srow + 32] = u1.e[j];
      }
    }

    for (int it = 0; it < ntiles; ++it) {
      const int buf = it & 1;
      __syncthreads();
      if (it + 1 < ntiles) {
        const int kv1 = (it + 1) * 64;
        ka0 = *(const uint4*)(Kh + (size_t)(kv1 + srow)      * 64 + scol);
        ka1 = *(const uint4*)(Kh + (size_t)(kv1 + srow + 32) * 64 + scol);
        va0 = *(const uint4*)(Vh + (size_t)(kv1 + srow)      * 64 + scol);
        va1 = *(const uint4*)(Vh + (size_t)(kv1 + srow + 32) * 64 + scol);
      }

      // S^T = K Q^T : lane holds q=l15; kv = hh*16 + l4*4 + r
      f32x4 s[4] = {};
      __builtin_amdgcn_s_setprio(1);
#pragma unroll
      for (int ks = 0; ks < 2; ++ks) {
        const s16x8 qf = ks ? qf1 : qf0;
#pragma unroll
        for (int hh = 0; hh < 4; ++hh) {
          const s16x8 kf = *(const s16x8*)&Ks[buf][hh * 16 + l15][ks * 32 + l4 * 8];
          s[hh] = MFMA(kf, qf, s[hh]);
        }
      }
      __builtin_amdgcn_s_setprio(0);

      if (it == ntiles - 1) {          // diagonal tile: causal mask
        const int kvb = it * 64 + l4 * 4;
        const int qg  = q0 + l15;
#pragma unroll
        for (int hh = 0; hh < 4; ++hh)
#pragma unroll
          for (int r = 0; r < 4; ++r)
            if (kvb + hh * 16 + r > qg) s[hh][r] = -3.0e38f;
      }

      float tmax = -3.0e38f;
#pragma unroll
      for (int hh = 0; hh < 4; ++hh)
#pragma unroll
        for (int r = 0; r < 4; ++r) tmax = fmaxf(tmax, s[hh][r]);
      tmax = fmaxf(tmax, __shfl_xor(tmax, 16));
      tmax = fmaxf(tmax, __shfl_xor(tmax, 32));

      if (__any(tmax > m + 8.0f)) {    // defer-max (exp2 domain)
        const float mn    = fmaxf(m, tmax);
        const float alpha = __builtin_amdgcn_exp2f(m - mn);
        m = mn;
        lr *= alpha;
#pragma unroll
        for (int n = 0; n < 4; ++n)
#pragma unroll
          for (int r = 0; r < 4; ++r) o[n][r] *= alpha;
      }

#pragma unroll
      for (int hh = 0; hh < 4; ++hh) {
        u16x4 pk;
#pragma unroll
        for (int r = 0; r < 4; ++r) {
          const float p = __builtin_amdgcn_exp2f(s[hh][r] - m);
          lr += p;
          pk[r] = f2bf(p);
        }
        *(u16x4*)&Ps[w][l15][hh * 16 + l4 * 4] = pk;
      }

      const s16x8 pf0 = *(const s16x8*)&Ps[w][l15][l4 * 8];
      const s16x8 pf1 = *(const s16x8*)&Ps[w][l15][32 + l4 * 8];
      __builtin_amdgcn_s_setprio(1);
#pragma unroll
      for (int n = 0; n < 4; ++n) {
        const s16x8 vf0 = *(const s16x8*)&Vs[buf][n * 16 + l15][l4 * 8];
        const s16x8 vf1 = *(const s16x8*)&Vs[buf][n * 16 + l15][32 + l4 * 8];
        o[n] = MFMA(vf0, pf0, o[n]);
        o[n] = MFMA(vf1, pf1, o[n]);
      }
      __builtin_amdgcn_s_setprio(0);

      if (it + 1 < ntiles) {
        const int nb = buf ^ 1;
        *(uint4*)&Ks[nb][srow][scol]      = ka0;
        *(uint4*)&Ks[nb][srow + 32][scol] = ka1;
        union { uint4 q; u16 e[8]; } u0, u1;
        u0.q = va0; u1.q = va1;
#pragma unroll
        for (int j = 0; j < 8; ++j) {
          Vs[nb][scol + j][srow]      = u0.e[j];
          Vs[nb][scol + j][srow + 32] = u1.e[j];
        }
      }
    }

    lr += __shfl_xor(lr, 16);
    lr += __shfl_xor(lr, 32);
    const float inv = 1.0f / lr;
    const int t = q0 + l15;
#pragma unroll
    for (int n = 0; n < 4; ++n) {
      u16x4 ov;
#pragma unroll
      for (int r = 0; r < 4; ++r) ov[r] = f2bf(o[n][r] * inv);
      *(u16x4*)(ob + (size_t)(b * Tn + t) * Dn + h * 64 + n * 16 + l4 * 4) = ov;
    }
  }
}

// ---------------------------------------------------------------------------
// Kernel 3: out = O @ W_o^T (M=4096, N=1024, K=1024), both operands bf16
// via global_load_lds (pure m97); fp32 output.
// ---------------------------------------------------------------------------
__global__ __launch_bounds__(256) void k_out(
    const u16* __restrict__ ob, const u16* __restrict__ wob,
    float* __restrict__ out)
{
  __shared__ u16 As[128 * 64];
  __shared__ u16 Bs[128 * 64];
  const int tid  = threadIdx.x;
  const int bcol = blockIdx.x;          // 8
  const int brow = blockIdx.y;          // 32
  const int lane = tid & 63, w = tid >> 6;
  const int wr = w >> 1, wc = w & 1;
  const int l15 = lane & 15, l4 = lane >> 4;
  const int lrow = lane >> 3, lcol = (lane & 7) * 8;

  f32x4 acc[4][4] = {};

  for (int k0 = 0; k0 < 1024; k0 += 64) {
#pragma unroll
    for (int c = 0; c < 4; ++c) {
      const int row = w * 32 + c * 8;
      lds16(&As[row * 64], ob  + (size_t)(brow * 128 + row + lrow) * 1024 + k0 + lcol);
      lds16(&Bs[row * 64], wob + (size_t)(bcol * 128 + row + lrow) * 1024 + k0 + lcol);
    }
    __syncthreads();
#pragma unroll
    for (int kk = 0; kk < 64; kk += 32) {
      s16x8 af[4], bf[4];
#pragma unroll
      for (int m = 0; m < 4; ++m)
        af[m] = *(const s16x8*)&As[(wr * 64 + m * 16 + l15) * 64 + kk + l4 * 8];
#pragma unroll
      for (int n = 0; n < 4; ++n)
        bf[n] = *(const s16x8*)&Bs[(wc * 64 + n * 16 + l15) * 64 + kk + l4 * 8];
#pragma unroll
      for (int m = 0; m < 4; ++m)
#pragma unroll
        for (int n = 0; n < 4; ++n)
          acc[m][n] = MFMA(af[m], bf[n], acc[m][n]);
    }
    __syncthreads();
  }

#pragma unroll
  for (int m = 0; m < 4; ++m) {
    const int rowb = brow * 128 + wr * 64 + m * 16 + l4 * 4;
#pragma unroll
    for (int n = 0; n < 4; ++n) {
      const int colg = bcol * 128 + wc * 64 + n * 16 + l15;
#pragma unroll
      for (int r = 0; r < 4; ++r)
        out[(size_t)(rowb + r) * 1024 + colg] = acc[m][n][r];
    }
  }
}

// ---------------------------------------------------------------------------
extern "C" void kernel_launch(void* const* d_in, const int* in_sizes, int n_in,
                              void* d_out, int out_size, void* d_ws, size_t ws_size,
                              hipStream_t stream) {
  const float* x      = (const float*)d_in[0];
  const int*   tokpos = (const int*)d_in[1];
  const float* wqkv   = (const float*)d_in[2];
  const float* wo     = (const float*)d_in[3];
  const float* cosc   = (const float*)d_in[4];
  const float* sinc   = (const float*)d_in[5];
  float* out = (float*)d_out;

  // workspace (u16 units): xb 4M (reused as ob), wqkvb 3M (reused as wob),
  // qb/kb/vb 4M each -> 19M u16 = 38 MB
  u16* xb    = (u16*)d_ws;
  u16* wqkvb = xb + (size_t)Bn * Tn * Dn;
  u16* qb    = wqkvb + (size_t)3 * Dn * Dn;
  u16* kb    = qb + (size_t)Bn * Tn * Dn;
  u16* vb    = kb + (size_t)Bn * Tn * Dn;
  u16* ob    = xb;      // xb dead after k_qkv
  u16* wob   = wqkvb;   // wqkvb dead after k_qkv

  dim3 blk(256);
  k_cvt<<<dim3(2048), blk, 0, stream>>>(x,    xb,    (Bn * Tn * Dn) / 4);
  k_cvt<<<dim3(2048), blk, 0, stream>>>(wqkv, wqkvb, (3 * Dn * Dn) / 4);

  k_qkv<<<dim3(24, 32), blk, 0, stream>>>(xb, wqkvb, tokpos, cosc, sinc, qb, kb, vb);

  k_cvt<<<dim3(1024), blk, 0, stream>>>(wo, wob, (Dn * Dn) / 4);

  k_attn<<<dim3(16, Bn * Hn), blk, 0, stream>>>(qb, kb, vb, ob);

  k_out<<<dim3(8, 32), blk, 0, stream>>>(ob, wob, out);
}

// Round 4
// 134.351 us; speedup vs baseline: 1.9398x; 1.2194x over previous
//
#include <hip/hip_runtime.h>
#include <hip/hip_bf16.h>
#include <stdint.h>

// Problem constants (B=2, T=2048, D=1024, H=16, DH=64)
#define Bn  2
#define Tn  2048
#define Dn  1024
#define Hn  16
#define DHn 64
#define QSCALE 0.1803368801111204f   // 0.125 * log2(e): fold softmax scale + exp2 into Q

typedef unsigned short u16;
typedef __attribute__((ext_vector_type(8))) short s16x8;            // 8 bf16 MFMA frag
typedef __attribute__((ext_vector_type(8))) unsigned short u16x8;
typedef __attribute__((ext_vector_type(4))) unsigned short u16x4;
typedef __attribute__((ext_vector_type(4))) float f32x4;

#define MFMA(a, b, c) __builtin_amdgcn_mfma_f32_16x16x32_bf16((a), (b), (c), 0, 0, 0)

__device__ __forceinline__ u16 f2bf(float f) {
  union { __hip_bfloat16 b; u16 u; } c;
  c.b = __float2bfloat16(f);
  return c.u;
}
__device__ __forceinline__ float bf2f(u16 u) {
  union { u16 u; __hip_bfloat16 b; } c;
  c.u = u;
  return __bfloat162float(c.b);
}

// async global->LDS, 16B per lane; LDS dest is wave-uniform base (+lane*16)
__device__ __forceinline__ void lds16(void* lds, const void* g) {
  __builtin_amdgcn_global_load_lds((__attribute__((address_space(1))) void*)(g),
                                   (__attribute__((address_space(3))) void*)(lds), 16, 0, 0);
}

// ---------------------------------------------------------------------------
// fp32 -> bf16 bulk convert
// ---------------------------------------------------------------------------
__global__ __launch_bounds__(256) void k_cvt(const float* __restrict__ src,
                                             u16* __restrict__ dst, int n4) {
  int i = blockIdx.x * blockDim.x + threadIdx.x;
  const int stride = gridDim.x * blockDim.x;
  for (; i < n4; i += stride) {
    float4 v = ((const float4*)src)[i];
    u16x4 o;
    o[0] = f2bf(v.x); o[1] = f2bf(v.y); o[2] = f2bf(v.z); o[3] = f2bf(v.w);
    ((u16x4*)dst)[i] = o;
  }
}

// ---------------------------------------------------------------------------
// Kernel 1: qkv = x @ W_qkv^T (M=4096, N=3072, K=1024), m97 main loop.
// Blocks are pure Q (bcol 0-7), K (8-15), or V (16-23).
// Epilogue: acc -> LDS tile; Q/K: in-register RoPE + coalesced row stores;
// V: column-read transpose -> V^T [b,h,dh,t] (16B scattered stores).
// ---------------------------------------------------------------------------
__global__ __launch_bounds__(256) void k_qkv(
    const u16* __restrict__ xb, const u16* __restrict__ wb,
    const int* __restrict__ tokpos,
    const float* __restrict__ cosc, const float* __restrict__ sinc,
    u16* __restrict__ qb, u16* __restrict__ kb, u16* __restrict__ vtb)
{
  __shared__ u16 smem[128 * 128];       // 32KB: main loop As|Bs, epilogue Ct[128][128]
  u16* As = smem;                       // [128][64] linear (global_load_lds)
  u16* Bs = smem + 128 * 64;
  const int tid  = threadIdx.x;
  const int bcol = blockIdx.x;          // 24 tiles of N=3072
  const int brow = blockIdx.y;          // 32 tiles of M=4096
  const int lane = tid & 63, w = tid >> 6;
  const int wr = w >> 1, wc = w & 1;
  const int l15 = lane & 15, l4 = lane >> 4;
  const int lrow = lane >> 3, lcol = (lane & 7) * 8;

  f32x4 acc[4][4] = {};

  for (int k0 = 0; k0 < 1024; k0 += 64) {
#pragma unroll
    for (int c = 0; c < 4; ++c) {
      const int row = w * 32 + c * 8;   // wave-uniform
      lds16(&As[row * 64], xb + (size_t)(brow * 128 + row + lrow) * 1024 + k0 + lcol);
      lds16(&Bs[row * 64], wb + (size_t)(bcol * 128 + row + lrow) * 1024 + k0 + lcol);
    }
    __syncthreads();
#pragma unroll
    for (int kk = 0; kk < 64; kk += 32) {
      s16x8 af[4], bf[4];
#pragma unroll
      for (int m = 0; m < 4; ++m)
        af[m] = *(const s16x8*)&As[(wr * 64 + m * 16 + l15) * 64 + kk + l4 * 8];
#pragma unroll
      for (int n = 0; n < 4; ++n)
        bf[n] = *(const s16x8*)&Bs[(wc * 64 + n * 16 + l15) * 64 + kk + l4 * 8];
#pragma unroll
      for (int m = 0; m < 4; ++m)
#pragma unroll
        for (int n = 0; n < 4; ++n)
          acc[m][n] = MFMA(af[m], bf[n], acc[m][n]);
    }
    __syncthreads();
  }

  // ---- epilogue phase 1: raw acc -> Ct (bf16, stride 128) ----
#pragma unroll
  for (int m = 0; m < 4; ++m)
#pragma unroll
    for (int n = 0; n < 4; ++n)
#pragma unroll
      for (int r = 0; r < 4; ++r)
        smem[(wr * 64 + m * 16 + l4 * 4 + r) * 128 + wc * 64 + n * 16 + l15] =
            f2bf(acc[m][n][r]);
  __syncthreads();

  if (bcol < 16) {
    // ---- Q/K: re-read rows, RoPE in-register, coalesced 16B stores ----
    u16* dst; float sc;
    if (bcol < 8) { dst = qb; sc = QSCALE; } else { dst = kb; sc = 1.0f; }
#pragma unroll
    for (int ph = 0; ph < 8; ++ph) {
      const int task = ph * 256 + tid;
      const int lr   = task >> 4;          // 0..127
      const int cg   = task & 15;          // col group (8 elems)
      const int rowg = brow * 128 + lr;
      const int b = rowg >> 11, t = rowg & 2047;
      const int rem = (bcol * 128 + cg * 8) & 1023;
      const int h = rem >> 6, dh0 = rem & 63;
      u16x8 v = *(const u16x8*)&smem[lr * 128 + cg * 8];
      const int pos = tokpos[t];
      const float4 cv = *(const float4*)&cosc[pos * 32 + (dh0 >> 1)];
      const float4 sv = *(const float4*)&sinc[pos * 32 + (dh0 >> 1)];
      const float cc[4] = {cv.x, cv.y, cv.z, cv.w};
      const float ss[4] = {sv.x, sv.y, sv.z, sv.w};
      u16x8 o;
#pragma unroll
      for (int p = 0; p < 4; ++p) {
        const float x1 = bf2f(v[2 * p]), x2 = bf2f(v[2 * p + 1]);
        o[2 * p]     = f2bf((x1 * cc[p] - x2 * ss[p]) * sc);
        o[2 * p + 1] = f2bf((x1 * ss[p] + x2 * cc[p]) * sc);
      }
      *(u16x8*)(dst + ((size_t)(b * Hn + h) * Tn + t) * DHn + dh0) = o;
    }
  } else {
    // ---- V: column read (conflict-free) -> V^T [b,h,dh,t] ----
    const int b  = (brow * 128) >> 11;     // block-uniform
    const int t0 = (brow * 128) & 2047;
#pragma unroll
    for (int ph = 0; ph < 8; ++ph) {
      const int task = ph * 256 + tid;
      const int col = task & 127;          // lane -> consecutive cols
      const int tg  = task >> 7;           // 0..15
      const int h  = 2 * (bcol - 16) + (col >> 6);
      const int dh = col & 63;
      u16x8 v;
#pragma unroll
      for (int j = 0; j < 8; ++j) v[j] = smem[(tg * 8 + j) * 128 + col];
      *(u16x8*)(vtb + ((size_t)(b * Hn + h) * DHn + dh) * Tn + t0 + tg * 8) = v;
    }
  }
}

// ---------------------------------------------------------------------------
// Kernel 2: causal flash attention, swapped-QK^T, KVBLK=64, double-buffered
// LDS with reg prefetch, paired q-tiles, XCD-swizzled 1D grid (512 blocks:
// all 16 q-blocks of a head land on one XCD -> K/V stay in its L2).
// ---------------------------------------------------------------------------
__global__ __launch_bounds__(256) void k_attn(
    const u16* __restrict__ qbuf, const u16* __restrict__ kbuf,
    const u16* __restrict__ vtb, u16* __restrict__ ob)
{
  __shared__ u16 Ks[2][64][72];   // [buf][kv][dh]
  __shared__ u16 Vs[2][64][72];   // [buf][dh][kv]
  __shared__ u16 Ps[4][16][72];   // per-wave P^T relayout [q][kv]

  const int tid  = threadIdx.x;
  const int lane = tid & 63, w = tid >> 6;
  const int l15 = lane & 15, l4 = lane >> 4;

  // XCD swizzle: lin = xcd + 8*(16*(bh/8) + bx) -> same-head blocks same XCD
  const int lin = blockIdx.x;
  const int xcd = lin & 7, kgrp = lin >> 3;
  const int bh  = xcd + 8 * (kgrp >> 4);
  const int bx  = kgrp & 15;
  const int b = bh >> 4, h = bh & 15;

  const u16* Qh = qbuf + (size_t)bh * Tn * DHn;
  const u16* Kh = kbuf + (size_t)bh * Tn * DHn;
  const u16* Vh = vtb  + (size_t)bh * DHn * Tn;

  const int srow = tid >> 3, scol = (tid & 7) * 8;

  for (int seg = 0; seg < 2; ++seg) {
    const int qblk = seg ? (31 - bx) : bx;           // uniform 33 tiles/block
    const int q0 = qblk * 64 + w * 16;
    const int ntiles = qblk + 1;

    const s16x8 qf0 = *(const s16x8*)(Qh + (size_t)(q0 + l15) * 64 + l4 * 8);
    const s16x8 qf1 = *(const s16x8*)(Qh + (size_t)(q0 + l15) * 64 + 32 + l4 * 8);

    f32x4 o[4] = {};
    float m = -3.0e38f, lr = 0.0f;

    uint4 ka0 = *(const uint4*)(Kh + (size_t)(srow)      * 64 + scol);
    uint4 ka1 = *(const uint4*)(Kh + (size_t)(srow + 32) * 64 + scol);
    uint4 va0 = *(const uint4*)(Vh + (size_t)(srow)      * Tn + scol);
    uint4 va1 = *(const uint4*)(Vh + (size_t)(srow + 32) * Tn + scol);
    __syncthreads();
    *(uint4*)&Ks[0][srow][scol]      = ka0;
    *(uint4*)&Ks[0][srow + 32][scol] = ka1;
    *(uint4*)&Vs[0][srow][scol]      = va0;
    *(uint4*)&Vs[0][srow + 32][scol] = va1;

    for (int it = 0; it < ntiles; ++it) {
      const int buf = it & 1;
      __syncthreads();
      if (it + 1 < ntiles) {
        const int kv1 = (it + 1) * 64;
        ka0 = *(const uint4*)(Kh + (size_t)(kv1 + srow)      * 64 + scol);
        ka1 = *(const uint4*)(Kh + (size_t)(kv1 + srow + 32) * 64 + scol);
        va0 = *(const uint4*)(Vh + (size_t)(srow)      * Tn + kv1 + scol);
        va1 = *(const uint4*)(Vh + (size_t)(srow + 32) * Tn + kv1 + scol);
      }

      // S^T = K Q^T : lane holds q=l15; kv = hh*16 + l4*4 + r
      f32x4 s[4] = {};
      __builtin_amdgcn_s_setprio(1);
#pragma unroll
      for (int ks = 0; ks < 2; ++ks) {
        const s16x8 qf = ks ? qf1 : qf0;
#pragma unroll
        for (int hh = 0; hh < 4; ++hh) {
          const s16x8 kf = *(const s16x8*)&Ks[buf][hh * 16 + l15][ks * 32 + l4 * 8];
          s[hh] = MFMA(kf, qf, s[hh]);
        }
      }
      __builtin_amdgcn_s_setprio(0);

      if (it == ntiles - 1) {          // diagonal tile: causal mask
        const int kvb = it * 64 + l4 * 4;
        const int qg  = q0 + l15;
#pragma unroll
        for (int hh = 0; hh < 4; ++hh)
#pragma unroll
          for (int r = 0; r < 4; ++r)
            if (kvb + hh * 16 + r > qg) s[hh][r] = -3.0e38f;
      }

      float tmax = -3.0e38f;
#pragma unroll
      for (int hh = 0; hh < 4; ++hh)
#pragma unroll
        for (int r = 0; r < 4; ++r) tmax = fmaxf(tmax, s[hh][r]);
      tmax = fmaxf(tmax, __shfl_xor(tmax, 16));
      tmax = fmaxf(tmax, __shfl_xor(tmax, 32));

      if (__any(tmax > m + 8.0f)) {    // defer-max (exp2 domain)
        const float mn    = fmaxf(m, tmax);
        const float alpha = __builtin_amdgcn_exp2f(m - mn);
        m = mn;
        lr *= alpha;
#pragma unroll
        for (int n = 0; n < 4; ++n)
#pragma unroll
          for (int r = 0; r < 4; ++r) o[n][r] *= alpha;
      }

#pragma unroll
      for (int hh = 0; hh < 4; ++hh) {
        u16x4 pk;
#pragma unroll
        for (int r = 0; r < 4; ++r) {
          const float p = __builtin_amdgcn_exp2f(s[hh][r] - m);
          lr += p;
          pk[r] = f2bf(p);
        }
        *(u16x4*)&Ps[w][l15][hh * 16 + l4 * 4] = pk;
      }

      const s16x8 pf0 = *(const s16x8*)&Ps[w][l15][l4 * 8];
      const s16x8 pf1 = *(const s16x8*)&Ps[w][l15][32 + l4 * 8];
      __builtin_amdgcn_s_setprio(1);
#pragma unroll
      for (int n = 0; n < 4; ++n) {
        const s16x8 vf0 = *(const s16x8*)&Vs[buf][n * 16 + l15][l4 * 8];
        const s16x8 vf1 = *(const s16x8*)&Vs[buf][n * 16 + l15][32 + l4 * 8];
        o[n] = MFMA(vf0, pf0, o[n]);
        o[n] = MFMA(vf1, pf1, o[n]);
      }
      __builtin_amdgcn_s_setprio(0);

      if (it + 1 < ntiles) {
        const int nb = buf ^ 1;
        *(uint4*)&Ks[nb][srow][scol]      = ka0;
        *(uint4*)&Ks[nb][srow + 32][scol] = ka1;
        *(uint4*)&Vs[nb][srow][scol]      = va0;
        *(uint4*)&Vs[nb][srow + 32][scol] = va1;
      }
    }

    lr += __shfl_xor(lr, 16);
    lr += __shfl_xor(lr, 32);
    const float inv = 1.0f / lr;
    const int t = q0 + l15;
#pragma unroll
    for (int n = 0; n < 4; ++n) {
      u16x4 ov;
#pragma unroll
      for (int r = 0; r < 4; ++r) ov[r] = f2bf(o[n][r] * inv);
      *(u16x4*)(ob + (size_t)(b * Tn + t) * Dn + h * 64 + n * 16 + l4 * 4) = ov;
    }
  }
}

// ---------------------------------------------------------------------------
// Kernel 3: out = O @ W_o^T (M=4096, N=1024, K=1024), both operands bf16
// via global_load_lds (pure m97); fp32 output.
// ---------------------------------------------------------------------------
__global__ __launch_bounds__(256) void k_out(
    const u16* __restrict__ ob, const u16* __restrict__ wob,
    float* __restrict__ out)
{
  __shared__ u16 As[128 * 64];
  __shared__ u16 Bs[128 * 64];
  const int tid  = threadIdx.x;
  const int bcol = blockIdx.x;          // 8
  const int brow = blockIdx.y;          // 32
  const int lane = tid & 63, w = tid >> 6;
  const int wr = w >> 1, wc = w & 1;
  const int l15 = lane & 15, l4 = lane >> 4;
  const int lrow = lane >> 3, lcol = (lane & 7) * 8;

  f32x4 acc[4][4] = {};

  for (int k0 = 0; k0 < 1024; k0 += 64) {
#pragma unroll
    for (int c = 0; c < 4; ++c) {
      const int row = w * 32 + c * 8;
      lds16(&As[row * 64], ob  + (size_t)(brow * 128 + row + lrow) * 1024 + k0 + lcol);
      lds16(&Bs[row * 64], wob + (size_t)(bcol * 128 + row + lrow) * 1024 + k0 + lcol);
    }
    __syncthreads();
#pragma unroll
    for (int kk = 0; kk < 64; kk += 32) {
      s16x8 af[4], bf[4];
#pragma unroll
      for (int m = 0; m < 4; ++m)
        af[m] = *(const s16x8*)&As[(wr * 64 + m * 16 + l15) * 64 + kk + l4 * 8];
#pragma unroll
      for (int n = 0; n < 4; ++n)
        bf[n] = *(const s16x8*)&Bs[(wc * 64 + n * 16 + l15) * 64 + kk + l4 * 8];
#pragma unroll
      for (int m = 0; m < 4; ++m)
#pragma unroll
        for (int n = 0; n < 4; ++n)
          acc[m][n] = MFMA(af[m], bf[n], acc[m][n]);
    }
    __syncthreads();
  }

#pragma unroll
  for (int m = 0; m < 4; ++m) {
    const int rowb = brow * 128 + wr * 64 + m * 16 + l4 * 4;
#pragma unroll
    for (int n = 0; n < 4; ++n) {
      const int colg = bcol * 128 + wc * 64 + n * 16 + l15;
#pragma unroll
      for (int r = 0; r < 4; ++r)
        out[(size_t)(rowb + r) * 1024 + colg] = acc[m][n][r];
    }
  }
}

// ---------------------------------------------------------------------------
extern "C" void kernel_launch(void* const* d_in, const int* in_sizes, int n_in,
                              void* d_out, int out_size, void* d_ws, size_t ws_size,
                              hipStream_t stream) {
  const float* x      = (const float*)d_in[0];
  const int*   tokpos = (const int*)d_in[1];
  const float* wqkv   = (const float*)d_in[2];
  const float* wo     = (const float*)d_in[3];
  const float* cosc   = (const float*)d_in[4];
  const float* sinc   = (const float*)d_in[5];
  float* out = (float*)d_out;

  // workspace (u16 units): xb 4M (reused as ob), wqkvb 3M (reused as wob),
  // qb/kb/vtb 4M each -> 19M u16 = 38 MB
  u16* xb    = (u16*)d_ws;
  u16* wqkvb = xb + (size_t)Bn * Tn * Dn;
  u16* qb    = wqkvb + (size_t)3 * Dn * Dn;
  u16* kb    = qb + (size_t)Bn * Tn * Dn;
  u16* vtb   = kb + (size_t)Bn * Tn * Dn;
  u16* ob    = xb;      // xb dead after k_qkv
  u16* wob   = wqkvb;   // wqkvb dead after k_qkv

  dim3 blk(256);
  k_cvt<<<dim3(2048), blk, 0, stream>>>(x,    xb,    (Bn * Tn * Dn) / 4);
  k_cvt<<<dim3(2048), blk, 0, stream>>>(wqkv, wqkvb, (3 * Dn * Dn) / 4);

  k_qkv<<<dim3(24, 32), blk, 0, stream>>>(xb, wqkvb, tokpos, cosc, sinc, qb, kb, vtb);

  k_cvt<<<dim3(1024), blk, 0, stream>>>(wo, wob, (Dn * Dn) / 4);

  k_attn<<<dim3(512), blk, 0, stream>>>(qb, kb, vtb, ob);

  k_out<<<dim3(8, 32), blk, 0, stream>>>(ob, wob, out);
}

// Round 5
// 107.085 us; speedup vs baseline: 2.4337x; 1.2546x over previous
//
#include <hip/hip_runtime.h>
#include <hip/hip_bf16.h>
#include <stdint.h>

// Problem constants (B=2, T=2048, D=1024, H=16, DH=64)
#define Bn  2
#define Tn  2048
#define Dn  1024
#define Hn  16
#define DHn 64
#define QSCALE 0.1803368801111204f   // 0.125 * log2(e): fold softmax scale + exp2 into Q

typedef unsigned short u16;
typedef __attribute__((ext_vector_type(8))) short s16x8;            // 8 bf16 MFMA frag
typedef __attribute__((ext_vector_type(8))) unsigned short u16x8;
typedef __attribute__((ext_vector_type(4))) unsigned short u16x4;
typedef __attribute__((ext_vector_type(4))) float f32x4;

#define MFMA(a, b, c) __builtin_amdgcn_mfma_f32_16x16x32_bf16((a), (b), (c), 0, 0, 0)

__device__ __forceinline__ u16 f2bf(float f) {
  union { __hip_bfloat16 b; u16 u; } c;
  c.b = __float2bfloat16(f);
  return c.u;
}
__device__ __forceinline__ float bf2f(u16 u) {
  union { u16 u; __hip_bfloat16 b; } c;
  c.u = u;
  return __bfloat162float(c.b);
}

// async global->LDS, 16B per lane; LDS dest is wave-uniform base (+lane*16)
__device__ __forceinline__ void lds16(void* lds, const void* g) {
  __builtin_amdgcn_global_load_lds((__attribute__((address_space(1))) void*)(g),
                                   (__attribute__((address_space(3))) void*)(lds), 16, 0, 0);
}

// ---------------------------------------------------------------------------
// fp32 -> bf16 bulk convert
// ---------------------------------------------------------------------------
__global__ __launch_bounds__(256) void k_cvt(const float* __restrict__ src,
                                             u16* __restrict__ dst, int n4) {
  int i = blockIdx.x * blockDim.x + threadIdx.x;
  const int stride = gridDim.x * blockDim.x;
  for (; i < n4; i += stride) {
    float4 v = ((const float4*)src)[i];
    u16x4 o;
    o[0] = f2bf(v.x); o[1] = f2bf(v.y); o[2] = f2bf(v.z); o[3] = f2bf(v.w);
    ((u16x4*)dst)[i] = o;
  }
}

// ---------------------------------------------------------------------------
// Kernel 1: qkv = x @ W_qkv^T (M=4096, N=3072, K=1024).
// 2-phase counted-vmcnt pipeline (dbuf LDS, 1 raw barrier/K-step, loads in
// flight during MFMA) + both-sides XOR granule swizzle (linear LDS dest,
// pre-swizzled global source, swizzled frag reads) -> conflict-free.
// Blocks are pure Q (bcol 0-7), K (8-15), or V (16-23). Epilogue: acc -> LDS
// (stride 136, padded); Q/K: in-register RoPE + coalesced stores; V: column
// transpose -> V^T [b,h,dh,t].
// ---------------------------------------------------------------------------
__global__ __launch_bounds__(256) void k_qkv(
    const u16* __restrict__ xb, const u16* __restrict__ wb,
    const int* __restrict__ tokpos,
    const float* __restrict__ cosc, const float* __restrict__ sinc,
    u16* __restrict__ qb, u16* __restrict__ kb, u16* __restrict__ vtb)
{
  __shared__ u16 smem[32768];           // 64KB: As0|As1|Bs0|Bs1 (16KB each); epilogue reuses
  const int tid  = threadIdx.x;
  const int bcol = blockIdx.x;          // 24 tiles of N=3072
  const int brow = blockIdx.y;          // 32 tiles of M=4096
  const int lane = tid & 63, w = tid >> 6;
  const int wr = w >> 1, wc = w & 1;
  const int l15 = lane & 15, l4 = lane >> 4;
  const int lrow = lane >> 3;
  const int gsw  = ((lane & 7) ^ (lane >> 3)) * 8;   // swizzled source granule (u16 units)
  const int rsw  = (l15 & 7);                        // frag-read row XOR

  f32x4 acc[4][4] = {};

  // prologue: stage K-tile 0 into buf0
#pragma unroll
  for (int c = 0; c < 4; ++c) {
    const int r0 = w * 32 + c * 8;
    lds16(&smem[r0 * 64],         xb + (size_t)(brow * 128 + r0 + lrow) * 1024 + gsw);
    lds16(&smem[16384 + r0 * 64], wb + (size_t)(bcol * 128 + r0 + lrow) * 1024 + gsw);
  }
  __syncthreads();

  for (int kt = 0; kt < 16; ++kt) {
    const int cur = kt & 1;
    const u16* Asb = smem + cur * 8192;
    const u16* Bsb = smem + 16384 + cur * 8192;
    if (kt < 15) {                       // issue next tile's loads (fly during MFMA)
      u16* Asn = smem + (cur ^ 1) * 8192;
      u16* Bsn = smem + 16384 + (cur ^ 1) * 8192;
      const int k1 = (kt + 1) * 64;
#pragma unroll
      for (int c = 0; c < 4; ++c) {
        const int r0 = w * 32 + c * 8;
        lds16(&Asn[r0 * 64], xb + (size_t)(brow * 128 + r0 + lrow) * 1024 + k1 + gsw);
        lds16(&Bsn[r0 * 64], wb + (size_t)(bcol * 128 + r0 + lrow) * 1024 + k1 + gsw);
      }
    }
    __builtin_amdgcn_s_setprio(1);
#pragma unroll
    for (int kk = 0; kk < 64; kk += 32) {
      const int gc = (kk >> 3) + l4;     // granule 0..7
      s16x8 af[4], bf[4];
#pragma unroll
      for (int m = 0; m < 4; ++m)
        af[m] = *(const s16x8*)&Asb[(wr * 64 + m * 16 + l15) * 64 + (gc ^ rsw) * 8];
#pragma unroll
      for (int n = 0; n < 4; ++n)
        bf[n] = *(const s16x8*)&Bsb[(wc * 64 + n * 16 + l15) * 64 + (gc ^ rsw) * 8];
#pragma unroll
      for (int m = 0; m < 4; ++m)
#pragma unroll
        for (int n = 0; n < 4; ++n)
          acc[m][n] = MFMA(af[m], bf[n], acc[m][n]);
    }
    __builtin_amdgcn_s_setprio(0);
    __builtin_amdgcn_sched_barrier(0);
    asm volatile("s_waitcnt vmcnt(0)" ::: "memory");  // drain prefetch (covered by MFMA)
    __builtin_amdgcn_s_barrier();
    __builtin_amdgcn_sched_barrier(0);
  }

  // ---- epilogue phase 1: raw acc -> Ct (bf16, stride 136 = padded) ----
#pragma unroll
  for (int m = 0; m < 4; ++m)
#pragma unroll
    for (int n = 0; n < 4; ++n)
#pragma unroll
      for (int r = 0; r < 4; ++r)
        smem[(wr * 64 + m * 16 + l4 * 4 + r) * 136 + wc * 64 + n * 16 + l15] =
            f2bf(acc[m][n][r]);
  __syncthreads();

  if (bcol < 16) {
    // ---- Q/K: re-read rows, RoPE in-register, coalesced 16B stores ----
    u16* dst; float sc;
    if (bcol < 8) { dst = qb; sc = QSCALE; } else { dst = kb; sc = 1.0f; }
#pragma unroll
    for (int ph = 0; ph < 8; ++ph) {
      const int task = ph * 256 + tid;
      const int lr   = task >> 4;          // 0..127
      const int cg   = task & 15;          // col group (8 elems)
      const int rowg = brow * 128 + lr;
      const int b = rowg >> 11, t = rowg & 2047;
      const int rem = (bcol * 128 + cg * 8) & 1023;
      const int h = rem >> 6, dh0 = rem & 63;
      u16x8 v = *(const u16x8*)&smem[lr * 136 + cg * 8];
      const int pos = tokpos[t];
      const float4 cv = *(const float4*)&cosc[pos * 32 + (dh0 >> 1)];
      const float4 sv = *(const float4*)&sinc[pos * 32 + (dh0 >> 1)];
      const float cc[4] = {cv.x, cv.y, cv.z, cv.w};
      const float ss[4] = {sv.x, sv.y, sv.z, sv.w};
      u16x8 o;
#pragma unroll
      for (int p = 0; p < 4; ++p) {
        const float x1 = bf2f(v[2 * p]), x2 = bf2f(v[2 * p + 1]);
        o[2 * p]     = f2bf((x1 * cc[p] - x2 * ss[p]) * sc);
        o[2 * p + 1] = f2bf((x1 * ss[p] + x2 * cc[p]) * sc);
      }
      *(u16x8*)(dst + ((size_t)(b * Hn + h) * Tn + t) * DHn + dh0) = o;
    }
  } else {
    // ---- V: column read (conflict-free) -> V^T [b,h,dh,t] ----
    const int b  = (brow * 128) >> 11;     // block-uniform
    const int t0 = (brow * 128) & 2047;
#pragma unroll
    for (int ph = 0; ph < 8; ++ph) {
      const int task = ph * 256 + tid;
      const int col = task & 127;          // lane -> consecutive cols
      const int tg  = task >> 7;           // 0..15
      const int h  = 2 * (bcol - 16) + (col >> 6);
      const int dh = col & 63;
      u16x8 v;
#pragma unroll
      for (int j = 0; j < 8; ++j) v[j] = smem[(tg * 8 + j) * 136 + col];
      *(u16x8*)(vtb + ((size_t)(b * Hn + h) * DHn + dh) * Tn + t0 + tg * 8) = v;
    }
  }
}

// ---------------------------------------------------------------------------
// Kernel 2: causal flash attention, swapped-QK^T, KVBLK=64, double-buffered
// LDS with reg prefetch, paired q-tiles, XCD-swizzled 1D grid (512 blocks:
// all 16 q-blocks of a head land on one XCD -> K/V stay in its L2).
// ---------------------------------------------------------------------------
__global__ __launch_bounds__(256) void k_attn(
    const u16* __restrict__ qbuf, const u16* __restrict__ kbuf,
    const u16* __restrict__ vtb, u16* __restrict__ ob)
{
  __shared__ u16 Ks[2][64][72];   // [buf][kv][dh]
  __shared__ u16 Vs[2][64][72];   // [buf][dh][kv]
  __shared__ u16 Ps[4][16][72];   // per-wave P^T relayout [q][kv]

  const int tid  = threadIdx.x;
  const int lane = tid & 63, w = tid >> 6;
  const int l15 = lane & 15, l4 = lane >> 4;

  // XCD swizzle: lin = xcd + 8*(16*(bh/8) + bx) -> same-head blocks same XCD
  const int lin = blockIdx.x;
  const int xcd = lin & 7, kgrp = lin >> 3;
  const int bh  = xcd + 8 * (kgrp >> 4);
  const int bx  = kgrp & 15;
  const int b = bh >> 4, h = bh & 15;

  const u16* Qh = qbuf + (size_t)bh * Tn * DHn;
  const u16* Kh = kbuf + (size_t)bh * Tn * DHn;
  const u16* Vh = vtb  + (size_t)bh * DHn * Tn;

  const int srow = tid >> 3, scol = (tid & 7) * 8;

  for (int seg = 0; seg < 2; ++seg) {
    const int qblk = seg ? (31 - bx) : bx;           // uniform 33 tiles/block
    const int q0 = qblk * 64 + w * 16;
    const int ntiles = qblk + 1;

    const s16x8 qf0 = *(const s16x8*)(Qh + (size_t)(q0 + l15) * 64 + l4 * 8);
    const s16x8 qf1 = *(const s16x8*)(Qh + (size_t)(q0 + l15) * 64 + 32 + l4 * 8);

    f32x4 o[4] = {};
    float m = -3.0e38f, lr = 0.0f;

    uint4 ka0 = *(const uint4*)(Kh + (size_t)(srow)      * 64 + scol);
    uint4 ka1 = *(const uint4*)(Kh + (size_t)(srow + 32) * 64 + scol);
    uint4 va0 = *(const uint4*)(Vh + (size_t)(srow)      * Tn + scol);
    uint4 va1 = *(const uint4*)(Vh + (size_t)(srow + 32) * Tn + scol);
    __syncthreads();
    *(uint4*)&Ks[0][srow][scol]      = ka0;
    *(uint4*)&Ks[0][srow + 32][scol] = ka1;
    *(uint4*)&Vs[0][srow][scol]      = va0;
    *(uint4*)&Vs[0][srow + 32][scol] = va1;

    for (int it = 0; it < ntiles; ++it) {
      const int buf = it & 1;
      __syncthreads();
      if (it + 1 < ntiles) {
        const int kv1 = (it + 1) * 64;
        ka0 = *(const uint4*)(Kh + (size_t)(kv1 + srow)      * 64 + scol);
        ka1 = *(const uint4*)(Kh + (size_t)(kv1 + srow + 32) * 64 + scol);
        va0 = *(const uint4*)(Vh + (size_t)(srow)      * Tn + kv1 + scol);
        va1 = *(const uint4*)(Vh + (size_t)(srow + 32) * Tn + kv1 + scol);
      }

      // S^T = K Q^T : lane holds q=l15; kv = hh*16 + l4*4 + r
      f32x4 s[4] = {};
      __builtin_amdgcn_s_setprio(1);
#pragma unroll
      for (int ks = 0; ks < 2; ++ks) {
        const s16x8 qf = ks ? qf1 : qf0;
#pragma unroll
        for (int hh = 0; hh < 4; ++hh) {
          const s16x8 kf = *(const s16x8*)&Ks[buf][hh * 16 + l15][ks * 32 + l4 * 8];
          s[hh] = MFMA(kf, qf, s[hh]);
        }
      }
      __builtin_amdgcn_s_setprio(0);

      if (it == ntiles - 1) {          // diagonal tile: causal mask
        const int kvb = it * 64 + l4 * 4;
        const int qg  = q0 + l15;
#pragma unroll
        for (int hh = 0; hh < 4; ++hh)
#pragma unroll
          for (int r = 0; r < 4; ++r)
            if (kvb + hh * 16 + r > qg) s[hh][r] = -3.0e38f;
      }

      float tmax = -3.0e38f;
#pragma unroll
      for (int hh = 0; hh < 4; ++hh)
#pragma unroll
        for (int r = 0; r < 4; ++r) tmax = fmaxf(tmax, s[hh][r]);
      tmax = fmaxf(tmax, __shfl_xor(tmax, 16));
      tmax = fmaxf(tmax, __shfl_xor(tmax, 32));

      if (__any(tmax > m + 8.0f)) {    // defer-max (exp2 domain)
        const float mn    = fmaxf(m, tmax);
        const float alpha = __builtin_amdgcn_exp2f(m - mn);
        m = mn;
        lr *= alpha;
#pragma unroll
        for (int n = 0; n < 4; ++n)
#pragma unroll
          for (int r = 0; r < 4; ++r) o[n][r] *= alpha;
      }

#pragma unroll
      for (int hh = 0; hh < 4; ++hh) {
        u16x4 pk;
#pragma unroll
        for (int r = 0; r < 4; ++r) {
          const float p = __builtin_amdgcn_exp2f(s[hh][r] - m);
          lr += p;
          pk[r] = f2bf(p);
        }
        *(u16x4*)&Ps[w][l15][hh * 16 + l4 * 4] = pk;
      }

      const s16x8 pf0 = *(const s16x8*)&Ps[w][l15][l4 * 8];
      const s16x8 pf1 = *(const s16x8*)&Ps[w][l15][32 + l4 * 8];
      __builtin_amdgcn_s_setprio(1);
#pragma unroll
      for (int n = 0; n < 4; ++n) {
        const s16x8 vf0 = *(const s16x8*)&Vs[buf][n * 16 + l15][l4 * 8];
        const s16x8 vf1 = *(const s16x8*)&Vs[buf][n * 16 + l15][32 + l4 * 8];
        o[n] = MFMA(vf0, pf0, o[n]);
        o[n] = MFMA(vf1, pf1, o[n]);
      }
      __builtin_amdgcn_s_setprio(0);

      if (it + 1 < ntiles) {
        const int nb = buf ^ 1;
        *(uint4*)&Ks[nb][srow][scol]      = ka0;
        *(uint4*)&Ks[nb][srow + 32][scol] = ka1;
        *(uint4*)&Vs[nb][srow][scol]      = va0;
        *(uint4*)&Vs[nb][srow + 32][scol] = va1;
      }
    }

    lr += __shfl_xor(lr, 16);
    lr += __shfl_xor(lr, 32);
    const float inv = 1.0f / lr;
    const int t = q0 + l15;
#pragma unroll
    for (int n = 0; n < 4; ++n) {
      u16x4 ov;
#pragma unroll
      for (int r = 0; r < 4; ++r) ov[r] = f2bf(o[n][r] * inv);
      *(u16x4*)(ob + (size_t)(b * Tn + t) * Dn + h * 64 + n * 16 + l4 * 4) = ov;
    }
  }
}

// ---------------------------------------------------------------------------
// Kernel 3: out = O @ W_o^T (M=4096, N=1024, K=1024), fp32 out.
// Tile 128x64 (grid 512 = 2 blocks/CU), same 2-phase pipeline + swizzle.
// ---------------------------------------------------------------------------
__global__ __launch_bounds__(256) void k_out(
    const u16* __restrict__ ob, const u16* __restrict__ wob,
    float* __restrict__ out)
{
  __shared__ u16 smem[24576];           // 48KB: As0|As1 (16KB) Bs0|Bs1 (8KB)
  const int tid  = threadIdx.x;
  const int bcol = blockIdx.x;          // 16 tiles of N=1024 (64 each)
  const int brow = blockIdx.y;          // 32 tiles of M=4096
  const int lane = tid & 63, w = tid >> 6;
  const int wr = w >> 1, wc = w & 1;    // wave quadrant: 64 rows x 32 cols
  const int l15 = lane & 15, l4 = lane >> 4;
  const int lrow = lane >> 3;
  const int gsw  = ((lane & 7) ^ (lane >> 3)) * 8;
  const int rsw  = (l15 & 7);

  f32x4 acc[4][2] = {};

#pragma unroll
  for (int c = 0; c < 4; ++c) {
    const int r0 = w * 32 + c * 8;
    lds16(&smem[r0 * 64], ob + (size_t)(brow * 128 + r0 + lrow) * 1024 + gsw);
  }
#pragma unroll
  for (int c = 0; c < 2; ++c) {
    const int r0 = w * 16 + c * 8;
    lds16(&smem[16384 + r0 * 64], wob + (size_t)(bcol * 64 + r0 + lrow) * 1024 + gsw);
  }
  __syncthreads();

  for (int kt = 0; kt < 16; ++kt) {
    const int cur = kt & 1;
    const u16* Asb = smem + cur * 8192;
    const u16* Bsb = smem + 16384 + cur * 4096;
    if (kt < 15) {
      u16* Asn = smem + (cur ^ 1) * 8192;
      u16* Bsn = smem + 16384 + (cur ^ 1) * 4096;
      const int k1 = (kt + 1) * 64;
#pragma unroll
      for (int c = 0; c < 4; ++c) {
        const int r0 = w * 32 + c * 8;
        lds16(&Asn[r0 * 64], ob + (size_t)(brow * 128 + r0 + lrow) * 1024 + k1 + gsw);
      }
#pragma unroll
      for (int c = 0; c < 2; ++c) {
        const int r0 = w * 16 + c * 8;
        lds16(&Bsn[r0 * 64], wob + (size_t)(bcol * 64 + r0 + lrow) * 1024 + k1 + gsw);
      }
    }
    __builtin_amdgcn_s_setprio(1);
#pragma unroll
    for (int kk = 0; kk < 64; kk += 32) {
      const int gc = (kk >> 3) + l4;
      s16x8 af[4], bf[2];
#pragma unroll
      for (int m = 0; m < 4; ++m)
        af[m] = *(const s16x8*)&Asb[(wr * 64 + m * 16 + l15) * 64 + (gc ^ rsw) * 8];
#pragma unroll
      for (int n = 0; n < 2; ++n)
        bf[n] = *(const s16x8*)&Bsb[(wc * 32 + n * 16 + l15) * 64 + (gc ^ rsw) * 8];
#pragma unroll
      for (int m = 0; m < 4; ++m)
#pragma unroll
        for (int n = 0; n < 2; ++n)
          acc[m][n] = MFMA(af[m], bf[n], acc[m][n]);
    }
    __builtin_amdgcn_s_setprio(0);
    __builtin_amdgcn_sched_barrier(0);
    asm volatile("s_waitcnt vmcnt(0)" ::: "memory");
    __builtin_amdgcn_s_barrier();
    __builtin_amdgcn_sched_barrier(0);
  }

#pragma unroll
  for (int m = 0; m < 4; ++m) {
    const int rowb = brow * 128 + wr * 64 + m * 16 + l4 * 4;
#pragma unroll
    for (int n = 0; n < 2; ++n) {
      const int colg = bcol * 64 + wc * 32 + n * 16 + l15;
#pragma unroll
      for (int r = 0; r < 4; ++r)
        out[(size_t)(rowb + r) * 1024 + colg] = acc[m][n][r];
    }
  }
}

// ---------------------------------------------------------------------------
extern "C" void kernel_launch(void* const* d_in, const int* in_sizes, int n_in,
                              void* d_out, int out_size, void* d_ws, size_t ws_size,
                              hipStream_t stream) {
  const float* x      = (const float*)d_in[0];
  const int*   tokpos = (const int*)d_in[1];
  const float* wqkv   = (const float*)d_in[2];
  const float* wo     = (const float*)d_in[3];
  const float* cosc   = (const float*)d_in[4];
  const float* sinc   = (const float*)d_in[5];
  float* out = (float*)d_out;

  // workspace (u16 units): xb 4M (reused as ob), wqkvb 3M (reused as wob),
  // qb/kb/vtb 4M each -> 19M u16 = 38 MB
  u16* xb    = (u16*)d_ws;
  u16* wqkvb = xb + (size_t)Bn * Tn * Dn;
  u16* qb    = wqkvb + (size_t)3 * Dn * Dn;
  u16* kb    = qb + (size_t)Bn * Tn * Dn;
  u16* vtb   = kb + (size_t)Bn * Tn * Dn;
  u16* ob    = xb;      // xb dead after k_qkv
  u16* wob   = wqkvb;   // wqkvb dead after k_qkv

  dim3 blk(256);
  k_cvt<<<dim3(2048), blk, 0, stream>>>(x,    xb,    (Bn * Tn * Dn) / 4);
  k_cvt<<<dim3(2048), blk, 0, stream>>>(wqkv, wqkvb, (3 * Dn * Dn) / 4);

  k_qkv<<<dim3(24, 32), blk, 0, stream>>>(xb, wqkvb, tokpos, cosc, sinc, qb, kb, vtb);

  k_cvt<<<dim3(1024), blk, 0, stream>>>(wo, wob, (Dn * Dn) / 4);

  k_attn<<<dim3(512), blk, 0, stream>>>(qb, kb, vtb, ob);

  k_out<<<dim3(16, 32), blk, 0, stream>>>(ob, wob, out);
}